// Round 2
// baseline (961.843 us; speedup 1.0000x reference)
//
#include <hip/hip_runtime.h>
#include <hip/hip_bf16.h>

// GCN3: 3-layer GCN on MI355X.
// x:[N,128] f32, edge_index:[2,E] i32, edge_weight:[E] f32,
// W1[128,128] b1[128] W2[128,128] b2[128] W3[128,64] b3[64]
// out: [N,64] f32

#define K_DIM 128

// ---------------- init: deg=1 (self loop), cnt=0 ----------------
__global__ void init_kernel(float* __restrict__ deg, int* __restrict__ cnt, int n) {
    int i = blockIdx.x * blockDim.x + threadIdx.x;
    if (i < n) { deg[i] = 1.0f; cnt[i] = 0; }
}

// ---------------- histogram: deg += ew at col, cnt++ ----------------
__global__ void hist_kernel(const int* __restrict__ col, const float* __restrict__ ew,
                            float* __restrict__ deg, int* __restrict__ cnt, int e) {
    int i = blockIdx.x * blockDim.x + threadIdx.x;
    if (i < e) {
        int c = col[i];
        atomicAdd(&deg[c], ew[i]);
        atomicAdd(&cnt[c], 1);
    }
}

// ---------------- dinv = rsqrt(deg) in place (deg >= 1 always) ----------------
__global__ void rsqrt_kernel(float* __restrict__ deg, int n) {
    int i = blockIdx.x * blockDim.x + threadIdx.x;
    if (i < n) deg[i] = rsqrtf(deg[i]);
}

// ---------------- single-block exclusive scan of cnt -> ptr; cnt becomes fill ptr ----------------
__global__ __launch_bounds__(1024) void scan_kernel(int* __restrict__ cnt,
                                                    int* __restrict__ ptr, int n) {
    __shared__ int wsum[16];
    int t = threadIdx.x;
    int lane = t & 63;
    int wid = t >> 6;
    int carry = 0;
    for (int base = 0; base < n; base += 1024) {
        int i = base + t;
        int x = (i < n) ? cnt[i] : 0;
        // wave inclusive scan
        int v = x;
        #pragma unroll
        for (int d = 1; d < 64; d <<= 1) {
            int y = __shfl_up(v, d, 64);
            if (lane >= d) v += y;
        }
        if (lane == 63) wsum[wid] = v;
        __syncthreads();
        if (wid == 0) {
            int s = (lane < 16) ? wsum[lane] : 0;
            #pragma unroll
            for (int d = 1; d < 16; d <<= 1) {
                int y = __shfl_up(s, d, 64);
                if (lane >= d) s += y;
            }
            if (lane < 16) wsum[lane] = s;  // inclusive over wave sums
        }
        __syncthreads();
        int woff = (wid > 0) ? wsum[wid - 1] : 0;
        int incl = v + woff;
        int excl = carry + incl - x;
        if (i < n) { ptr[i] = excl; cnt[i] = excl; }  // cnt reused as fill pointer
        carry += wsum[15];
        __syncthreads();  // protect wsum before overwrite next iter
    }
    if (t == 0) ptr[n] = carry;
}

// ---------------- scatter edges into CSC slots ----------------
__global__ void fill_kernel(const int* __restrict__ row, const int* __restrict__ col,
                            const float* __restrict__ ew, const float* __restrict__ dinv,
                            int* __restrict__ fillp, int* __restrict__ csr_row,
                            float* __restrict__ csr_w, int e) {
    int i = blockIdx.x * blockDim.x + threadIdx.x;
    if (i < e) {
        int c = col[i];
        int p = atomicAdd(&fillp[c], 1);
        int r = row[i];
        csr_row[p] = r;
        csr_w[p] = ew[i] * dinv[r];
    }
}

// ---------------- dense GEMM: T[nrows,DOUT] = A[nrows,128] @ W[128,DOUT] ----------------
template <int DOUT>
__global__ __launch_bounds__(256) void gemm_kernel(const float* __restrict__ A,
                                                   const float* __restrict__ W,
                                                   float* __restrict__ T, int nrows) {
    constexpr int K = K_DIM;
    constexpr int BM = 64;
    constexpr int TM = 4;          // rows per thread
    constexpr int TN = DOUT / 16;  // cols per thread (8 for 128, 4 for 64)
    __shared__ float Ws[K * DOUT];   // 64KB or 32KB
    __shared__ float Xs[K][72];      // transposed X tile [k][row], padded (288B rows, 16B aligned)
    int t = threadIdx.x;

    // load W into LDS (float4, coalesced)
    constexpr int WV = K * DOUT / 4;
    const float4* W4 = (const float4*)W;
    float4* Ws4 = (float4*)Ws;
    for (int i = t; i < WV; i += 256) Ws4[i] = W4[i];

    // load X tile transposed into LDS
    int row0 = blockIdx.x * BM;
    constexpr int XV = BM * K / 4;  // 2048 float4
    for (int i = t; i < XV; i += 256) {
        int r = i >> 5;      // 32 float4 per row
        int c4 = i & 31;
        float4 v = make_float4(0.f, 0.f, 0.f, 0.f);
        int gr = row0 + r;
        if (gr < nrows) v = ((const float4*)(A + (size_t)gr * K))[c4];
        Xs[c4 * 4 + 0][r] = v.x;
        Xs[c4 * 4 + 1][r] = v.y;
        Xs[c4 * 4 + 2][r] = v.z;
        Xs[c4 * 4 + 3][r] = v.w;
    }
    __syncthreads();

    int tx = t & 15;   // col group
    int ty = t >> 4;   // row group
    float acc[TM][TN] = {};
    #pragma unroll 4
    for (int k = 0; k < K; ++k) {
        float a[TM];
        float4 av = *(const float4*)&Xs[k][ty * 4];
        a[0] = av.x; a[1] = av.y; a[2] = av.z; a[3] = av.w;
        float b[TN];
        #pragma unroll
        for (int n4 = 0; n4 < TN / 4; ++n4) {
            float4 bv = *(const float4*)&Ws[k * DOUT + tx * TN + n4 * 4];
            b[n4 * 4 + 0] = bv.x; b[n4 * 4 + 1] = bv.y;
            b[n4 * 4 + 2] = bv.z; b[n4 * 4 + 3] = bv.w;
        }
        #pragma unroll
        for (int m = 0; m < TM; ++m)
            #pragma unroll
            for (int n = 0; n < TN; ++n) acc[m][n] += a[m] * b[n];
    }

    #pragma unroll
    for (int m = 0; m < TM; ++m) {
        int gr = row0 + ty * TM + m;
        if (gr < nrows) {
            #pragma unroll
            for (int n4 = 0; n4 < TN / 4; ++n4) {
                float4 v;
                v.x = acc[m][n4 * 4 + 0]; v.y = acc[m][n4 * 4 + 1];
                v.z = acc[m][n4 * 4 + 2]; v.w = acc[m][n4 * 4 + 3];
                *(float4*)&T[(size_t)gr * DOUT + tx * TN + n4 * 4] = v;
            }
        }
    }
}

// ---------------- aggregation: out[i] = relu?(dinv[i]*(sum_e csr_w*T[row] + dinv[i]*T[i]) + b) ----------------
template <int DOUT, bool RELU>
__global__ __launch_bounds__(256) void agg_kernel(const float* __restrict__ T,
                                                  const int* __restrict__ ptr,
                                                  const int* __restrict__ csr_row,
                                                  const float* __restrict__ csr_w,
                                                  const float* __restrict__ dinv,
                                                  const float* __restrict__ bias,
                                                  float* __restrict__ out, int n) {
    int wid = blockIdx.x * (blockDim.x >> 6) + (threadIdx.x >> 6);
    int lane = threadIdx.x & 63;
    if (wid >= n) return;
    int node = wid;
    int s = ptr[node];
    int e = ptr[node + 1];
    float di = dinv[node];

    if (DOUT == 128) {
        const float2* Tv = (const float2*)T;
        float2 acc = make_float2(0.f, 0.f);
        int k = s;
        for (; k + 1 < e; k += 2) {
            int r0 = csr_row[k], r1 = csr_row[k + 1];
            float w0 = csr_w[k], w1 = csr_w[k + 1];
            float2 h0 = Tv[(size_t)r0 * 64 + lane];
            float2 h1 = Tv[(size_t)r1 * 64 + lane];
            acc.x += w0 * h0.x; acc.y += w0 * h0.y;
            acc.x += w1 * h1.x; acc.y += w1 * h1.y;
        }
        if (k < e) {
            int r0 = csr_row[k];
            float w0 = csr_w[k];
            float2 h0 = Tv[(size_t)r0 * 64 + lane];
            acc.x += w0 * h0.x; acc.y += w0 * h0.y;
        }
        float2 hs = Tv[(size_t)node * 64 + lane];
        acc.x += di * hs.x; acc.y += di * hs.y;
        float2 bv = ((const float2*)bias)[lane];
        float ox = di * acc.x + bv.x;
        float oy = di * acc.y + bv.y;
        if (RELU) { ox = fmaxf(ox, 0.f); oy = fmaxf(oy, 0.f); }
        ((float2*)out)[(size_t)node * 64 + lane] = make_float2(ox, oy);
    } else {  // DOUT == 64, one float per lane
        float acc = 0.f;
        int k = s;
        for (; k + 1 < e; k += 2) {
            int r0 = csr_row[k], r1 = csr_row[k + 1];
            float w0 = csr_w[k], w1 = csr_w[k + 1];
            float h0 = T[(size_t)r0 * 64 + lane];
            float h1 = T[(size_t)r1 * 64 + lane];
            acc += w0 * h0;
            acc += w1 * h1;
        }
        if (k < e) {
            acc += csr_w[k] * T[(size_t)csr_row[k] * 64 + lane];
        }
        acc += di * T[(size_t)node * 64 + lane];
        float o = di * acc + bias[lane];
        if (RELU) o = fmaxf(o, 0.f);
        out[(size_t)node * 64 + lane] = o;
    }
}

extern "C" void kernel_launch(void* const* d_in, const int* in_sizes, int n_in,
                              void* d_out, int out_size, void* d_ws, size_t ws_size,
                              hipStream_t stream) {
    const float* x   = (const float*)d_in[0];
    const int* eidx  = (const int*)d_in[1];
    const float* ew  = (const float*)d_in[2];
    const float* W1  = (const float*)d_in[3];
    const float* b1  = (const float*)d_in[4];
    const float* W2  = (const float*)d_in[5];
    const float* b2  = (const float*)d_in[6];
    const float* W3  = (const float*)d_in[7];
    const float* b3  = (const float*)d_in[8];

    const int N = in_sizes[0] / K_DIM;
    const int E = in_sizes[2];
    const int* erow = eidx;
    const int* ecol = eidx + E;

    // workspace carve-up (256B aligned); total ~116 MB
    size_t off = 0;
    auto carve = [&](size_t bytes) {
        char* p = (char*)d_ws + off;
        off += (bytes + 255) & ~(size_t)255;
        return (void*)p;
    };
    float* dinv    = (float*)carve((size_t)N * 4);        // deg then dinv in place
    int*   cnt     = (int*)carve((size_t)N * 4);          // cnt, then fill pointer
    int*   ptr     = (int*)carve((size_t)(N + 1) * 4);
    int*   csr_row = (int*)carve((size_t)E * 4);
    float* csr_w   = (float*)carve((size_t)E * 4);
    float* T       = (float*)carve((size_t)N * 128 * 4);
    float* H       = (float*)carve((size_t)N * 128 * 4);
    (void)ws_size;

    float* out = (float*)d_out;

    const int BT = 256;
    int gN = (N + BT - 1) / BT;
    int gE = (E + BT - 1) / BT;

    // norm precompute + CSC build
    init_kernel<<<gN, BT, 0, stream>>>(dinv, cnt, N);
    hist_kernel<<<gE, BT, 0, stream>>>(ecol, ew, dinv, cnt, E);
    rsqrt_kernel<<<gN, BT, 0, stream>>>(dinv, N);
    scan_kernel<<<1, 1024, 0, stream>>>(cnt, ptr, N);
    fill_kernel<<<gE, BT, 0, stream>>>(erow, ecol, ew, dinv, cnt, csr_row, csr_w, E);

    int gGemm = (N + 63) / 64;
    int gAgg  = (N + 3) / 4;  // 4 waves per block, 1 node per wave

    // layer 1: T = x@W1 ; H = relu(agg(T) + b1)
    gemm_kernel<128><<<gGemm, 256, 0, stream>>>(x, W1, T, N);
    agg_kernel<128, true><<<gAgg, 256, 0, stream>>>(T, ptr, csr_row, csr_w, dinv, b1, H, N);

    // layer 2: T = H@W2 ; H = relu(agg(T) + b2)
    gemm_kernel<128><<<gGemm, 256, 0, stream>>>(H, W2, T, N);
    agg_kernel<128, true><<<gAgg, 256, 0, stream>>>(T, ptr, csr_row, csr_w, dinv, b2, H, N);

    // layer 3: T = H@W3 (N x 64) ; out = agg(T) + b3
    gemm_kernel<64><<<gGemm, 256, 0, stream>>>(H, W3, T, N);
    agg_kernel<64, false><<<gAgg, 256, 0, stream>>>(T, ptr, csr_row, csr_w, dinv, b3, out, N);
}

// Round 6
// 853.771 us; speedup vs baseline: 1.1266x; 1.1266x over previous
//
#include <hip/hip_runtime.h>
#include <hip/hip_bf16.h>
#include <hip/hip_fp16.h>

// GCN3: 3-layer GCN on MI355X (f32 inputs, fp16 internal message matrix).
// out[i] = dinv[i]*(sum_e ew*Ts[row_e] + Ts[i]) + b, Ts[r] = dinv[r]*(h@W)[r]
// CSC is canonicalized (per-node segment sort) so every call is bit-deterministic.

#define K_DIM 128

using h2 = __attribute__((ext_vector_type(2))) _Float16;
using h4 = __attribute__((ext_vector_type(4))) _Float16;

// ---------------- zero counts ----------------
__global__ void zero_kernel(int* __restrict__ cnt, int n) {
    int i = blockIdx.x * blockDim.x + threadIdx.x;
    if (i < n) cnt[i] = 0;
}

// ---------------- histogram: cnt[col]++ (single atomic per edge) ----------------
__global__ void hist_kernel(const int* __restrict__ col, int* __restrict__ cnt, int e) {
    int i = blockIdx.x * blockDim.x + threadIdx.x;
    if (i < e) atomicAdd(&cnt[col[i]], 1);
}

// ---------------- scan part A: per-block exclusive scan + block sums ----------------
__global__ __launch_bounds__(1024) void scanA_kernel(const int* __restrict__ cnt,
                                                     int* __restrict__ excl,   // -> ptr
                                                     int* __restrict__ bsum, int n) {
    __shared__ int wsum[16];
    int t = threadIdx.x, lane = t & 63, wid = t >> 6;
    int i = blockIdx.x * 1024 + t;
    int x = (i < n) ? cnt[i] : 0;
    int v = x;
    #pragma unroll
    for (int d = 1; d < 64; d <<= 1) {
        int y = __shfl_up(v, d, 64);
        if (lane >= d) v += y;
    }
    if (lane == 63) wsum[wid] = v;
    __syncthreads();
    if (wid == 0) {
        int s = (lane < 16) ? wsum[lane] : 0;
        #pragma unroll
        for (int d = 1; d < 16; d <<= 1) {
            int y = __shfl_up(s, d, 64);
            if (lane >= d) s += y;
        }
        if (lane < 16) wsum[lane] = s;
    }
    __syncthreads();
    int woff = (wid > 0) ? wsum[wid - 1] : 0;
    int incl = v + woff;
    if (i < n) excl[i] = incl - x;
    if (t == 1023) bsum[blockIdx.x] = incl;  // block total
}

// ---------------- scan part B: add block offsets; write ptr and fill ptr ----------------
__global__ __launch_bounds__(1024) void scanB_kernel(int* __restrict__ ptr,
                                                     int* __restrict__ fillp,
                                                     const int* __restrict__ bsum,
                                                     int n, int etot) {
    __shared__ int wred[16];
    __shared__ int off_s;
    int t = threadIdx.x, lane = t & 63, wid = t >> 6;
    int p = (t < blockIdx.x) ? bsum[t] : 0;   // blockIdx.x <= 97 < 1024
    #pragma unroll
    for (int d = 32; d; d >>= 1) p += __shfl_down(p, d, 64);
    if (lane == 0) wred[wid] = p;
    __syncthreads();
    if (t == 0) {
        int o = 0;
        #pragma unroll
        for (int j = 0; j < 16; ++j) o += wred[j];
        off_s = o;
    }
    __syncthreads();
    int off = off_s;
    int i = blockIdx.x * 1024 + t;
    if (i < n) {
        int val = ptr[i] + off;
        ptr[i] = val;
        fillp[i] = val;
    }
    if (blockIdx.x == 0 && t == 0) ptr[n] = etot;
}

// ---------------- scatter edges into CSC slots (packed 8B write) ----------------
__global__ void fill_kernel(const int* __restrict__ row, const int* __restrict__ col,
                            const float* __restrict__ ew, int* __restrict__ fillp,
                            int2* __restrict__ csr, int e) {
    int i = blockIdx.x * blockDim.x + threadIdx.x;
    if (i < e) {
        int c = col[i];
        int p = atomicAdd(&fillp[c], 1);
        csr[p] = make_int2(row[i], __float_as_int(ew[i]));
    }
}

// ---------------- canonicalize: per-node insertion sort of CSC segment ----------------
// Makes csr bit-deterministic regardless of fill's atomic arrival order, so every
// downstream reduction has a fixed summation order (replays are bit-identical).
__global__ void sort_kernel(int2* __restrict__ csr, const int* __restrict__ ptr, int n) {
    int i = blockIdx.x * blockDim.x + threadIdx.x;
    if (i >= n) return;
    int s = ptr[i], e = ptr[i + 1];
    for (int k = s + 1; k < e; ++k) {
        int2 key = csr[k];
        int j = k - 1;
        while (j >= s) {
            int2 cj = csr[j];
            bool gt = (cj.x > key.x) ||
                      (cj.x == key.x && (unsigned)cj.y > (unsigned)key.y);
            if (!gt) break;
            csr[j + 1] = cj;
            --j;
        }
        csr[j + 1] = key;
    }
}

// ---------------- weighted degree from CSC segments -> dinv (no atomics) ----------------
__global__ void deg_kernel(const int2* __restrict__ csr, const int* __restrict__ ptr,
                           float* __restrict__ dinv, int n) {
    int i = blockIdx.x * blockDim.x + threadIdx.x;
    if (i >= n) return;
    int s = ptr[i], e = ptr[i + 1];
    float sum = 1.0f;  // self-loop weight
    for (int k = s; k < e; ++k) sum += __int_as_float(csr[k].y);
    dinv[i] = rsqrtf(sum);
}

// ---------------- GEMM: Ts[r, col0:col0+64] = dinv[r] * (A[r,:] @ W[:, col0:col0+64]) ----------------
template <int DOUT, bool FP16OUT>
__global__ __launch_bounds__(256, 2) void gemm_kernel(const float* __restrict__ A,
                                                      const float* __restrict__ W,
                                                      const float* __restrict__ dinv,
                                                      void* __restrict__ Tout, int nrows) {
    constexpr int K = K_DIM;
    constexpr int BM = 64, BN = 64, TM = 4, TN = 4;
    __shared__ float Ws[K][BN];       // 32 KB
    __shared__ float Xs[K][BM + 8];   // 36 KB, transposed X tile, padded
    int t = threadIdx.x;
    int col0 = blockIdx.y * BN;

    // stage W columns [col0, col0+BN)
    const float4* W4 = (const float4*)W;
    for (int i = t; i < K * BN / 4; i += 256) {
        int k = i >> 4;    // BN/4 = 16 float4 per k-row
        int c4 = i & 15;
        float4 v = W4[k * (DOUT / 4) + (col0 >> 2) + c4];
        Ws[k][c4 * 4 + 0] = v.x; Ws[k][c4 * 4 + 1] = v.y;
        Ws[k][c4 * 4 + 2] = v.z; Ws[k][c4 * 4 + 3] = v.w;
    }
    // stage X tile transposed
    int row0 = blockIdx.x * BM;
    for (int i = t; i < BM * K / 4; i += 256) {
        int r = i >> 5;    // K/4 = 32 float4 per row
        int c4 = i & 31;
        float4 v = make_float4(0.f, 0.f, 0.f, 0.f);
        int gr = row0 + r;
        if (gr < nrows) v = ((const float4*)(A + (size_t)gr * K))[c4];
        Xs[c4 * 4 + 0][r] = v.x; Xs[c4 * 4 + 1][r] = v.y;
        Xs[c4 * 4 + 2][r] = v.z; Xs[c4 * 4 + 3][r] = v.w;
    }
    __syncthreads();

    int tx = t & 15;   // -> cols col0 + tx*4
    int ty = t >> 4;   // -> rows row0 + ty*4
    float acc[TM][TN] = {};
    #pragma unroll 8
    for (int k = 0; k < K; ++k) {
        float4 av = *(const float4*)&Xs[k][ty * 4];   // broadcast, conflict-free
        float4 bv = *(const float4*)&Ws[k][tx * 4];   // 2-way (free)
        float a[4] = {av.x, av.y, av.z, av.w};
        float b[4] = {bv.x, bv.y, bv.z, bv.w};
        #pragma unroll
        for (int m = 0; m < TM; ++m)
            #pragma unroll
            for (int n = 0; n < TN; ++n) acc[m][n] += a[m] * b[n];
    }

    #pragma unroll
    for (int m = 0; m < TM; ++m) {
        int gr = row0 + ty * TM + m;
        if (gr >= nrows) continue;
        float di = dinv[gr];
        if constexpr (FP16OUT) {
            h4 hv;
            #pragma unroll
            for (int n = 0; n < TN; ++n) hv[n] = (_Float16)(acc[m][n] * di);
            *(h4*)((_Float16*)Tout + (size_t)gr * DOUT + col0 + tx * TN) = hv;
        } else {
            float4 v;
            v.x = acc[m][0] * di; v.y = acc[m][1] * di;
            v.z = acc[m][2] * di; v.w = acc[m][3] * di;
            *(float4*)((float*)Tout + (size_t)gr * DOUT + col0 + tx * TN) = v;
        }
    }
}

// ---------------- aggregation, D=128 fp16 T: H[i] = relu(dinv[i]*(sum ew*Ts[row] + Ts[i]) + b) ----------------
template <bool RELU>
__global__ __launch_bounds__(256) void agg_f16_kernel(const _Float16* __restrict__ T,
                                                      const int* __restrict__ ptr,
                                                      const int2* __restrict__ csr,
                                                      const float* __restrict__ dinv,
                                                      const float* __restrict__ bias,
                                                      float* __restrict__ out, int n) {
    int wid = blockIdx.x * 4 + (threadIdx.x >> 6);
    int lane = threadIdx.x & 63;
    if (wid >= n) return;
    int s = ptr[wid], e = ptr[wid + 1];
    float di = dinv[wid];
    const h2* Tv = (const h2*)T;   // row = 64 x h2
    float ax = 0.f, ay = 0.f;
    int k = s;
    for (; k + 1 < e; k += 2) {
        int2 e0 = csr[k], e1 = csr[k + 1];
        h2 v0 = Tv[(size_t)e0.x * 64 + lane];
        h2 v1 = Tv[(size_t)e1.x * 64 + lane];
        float w0 = __int_as_float(e0.y), w1 = __int_as_float(e1.y);
        ax += w0 * (float)v0.x; ay += w0 * (float)v0.y;
        ax += w1 * (float)v1.x; ay += w1 * (float)v1.y;
    }
    if (k < e) {
        int2 e0 = csr[k];
        h2 v0 = Tv[(size_t)e0.x * 64 + lane];
        float w0 = __int_as_float(e0.y);
        ax += w0 * (float)v0.x; ay += w0 * (float)v0.y;
    }
    h2 hs = Tv[(size_t)wid * 64 + lane];  // self term: + Ts[i]
    ax += (float)hs.x; ay += (float)hs.y;
    float2 bv = ((const float2*)bias)[lane];
    float ox = di * ax + bv.x;
    float oy = di * ay + bv.y;
    if (RELU) { ox = fmaxf(ox, 0.f); oy = fmaxf(oy, 0.f); }
    ((float2*)out)[(size_t)wid * 64 + lane] = make_float2(ox, oy);
}

// ---------------- aggregation, D=64 f32 T (layer 3) ----------------
__global__ __launch_bounds__(256) void agg_f32_64_kernel(const float* __restrict__ T,
                                                         const int* __restrict__ ptr,
                                                         const int2* __restrict__ csr,
                                                         const float* __restrict__ dinv,
                                                         const float* __restrict__ bias,
                                                         float* __restrict__ out, int n) {
    int wid = blockIdx.x * 4 + (threadIdx.x >> 6);
    int lane = threadIdx.x & 63;
    if (wid >= n) return;
    int s = ptr[wid], e = ptr[wid + 1];
    float di = dinv[wid];
    float acc = 0.f;
    int k = s;
    for (; k + 1 < e; k += 2) {
        int2 e0 = csr[k], e1 = csr[k + 1];
        float h0 = T[(size_t)e0.x * 64 + lane];
        float h1 = T[(size_t)e1.x * 64 + lane];
        acc += __int_as_float(e0.y) * h0;
        acc += __int_as_float(e1.y) * h1;
    }
    if (k < e) {
        int2 e0 = csr[k];
        acc += __int_as_float(e0.y) * T[(size_t)e0.x * 64 + lane];
    }
    acc += T[(size_t)wid * 64 + lane];  // self term
    out[(size_t)wid * 64 + lane] = di * acc + bias[lane];
}

extern "C" void kernel_launch(void* const* d_in, const int* in_sizes, int n_in,
                              void* d_out, int out_size, void* d_ws, size_t ws_size,
                              hipStream_t stream) {
    const float* x   = (const float*)d_in[0];
    const int* eidx  = (const int*)d_in[1];
    const float* ew  = (const float*)d_in[2];
    const float* W1  = (const float*)d_in[3];
    const float* b1  = (const float*)d_in[4];
    const float* W2  = (const float*)d_in[5];
    const float* b2  = (const float*)d_in[6];
    const float* W3  = (const float*)d_in[7];
    const float* b3  = (const float*)d_in[8];

    const int N = in_sizes[0] / K_DIM;
    const int E = in_sizes[2];
    const int* erow = eidx;
    const int* ecol = eidx + E;

    size_t off = 0;
    auto carve = [&](size_t bytes) {
        char* p = (char*)d_ws + off;
        off += (bytes + 255) & ~(size_t)255;
        return (void*)p;
    };
    int*   cnt  = (int*)carve((size_t)N * 4);          // counts, then fill pointers
    int*   ptr  = (int*)carve((size_t)(N + 1) * 4);    // CSC offsets
    int*   bsum = (int*)carve(128 * 4);                // block sums for scan
    float* dinv = (float*)carve((size_t)N * 4);
    int2*  csr  = (int2*)carve((size_t)E * 8);         // packed {row, ew_bits}
    _Float16* Tf = (_Float16*)carve((size_t)N * 128 * 2);  // fp16 Ts (layers 1-2)
    float* H    = (float*)carve((size_t)N * 128 * 4);      // f32 activations
    float* T3   = (float*)carve((size_t)N * 64 * 4);       // f32 Ts (layer 3)
    (void)ws_size;

    float* out = (float*)d_out;

    const int BT = 256;
    int gN = (N + BT - 1) / BT;
    int gE = (E + BT - 1) / BT;
    int nScan = (N + 1023) / 1024;

    // ---- CSC build + canonicalize + norm ----
    zero_kernel<<<gN, BT, 0, stream>>>(cnt, N);
    hist_kernel<<<gE, BT, 0, stream>>>(ecol, cnt, E);
    scanA_kernel<<<nScan, 1024, 0, stream>>>(cnt, ptr, bsum, N);
    scanB_kernel<<<nScan, 1024, 0, stream>>>(ptr, cnt, bsum, N, E);
    fill_kernel<<<gE, BT, 0, stream>>>(erow, ecol, ew, cnt, csr, E);
    sort_kernel<<<gN, BT, 0, stream>>>(csr, ptr, N);
    deg_kernel<<<gN, BT, 0, stream>>>(csr, ptr, dinv, N);

    dim3 gG128((N + 63) / 64, 2);
    dim3 gG64((N + 63) / 64, 1);
    int gAgg = (N + 3) / 4;

    // layer 1
    gemm_kernel<128, true><<<gG128, 256, 0, stream>>>(x, W1, dinv, Tf, N);
    agg_f16_kernel<true><<<gAgg, 256, 0, stream>>>(Tf, ptr, csr, dinv, b1, H, N);
    // layer 2
    gemm_kernel<128, true><<<gG128, 256, 0, stream>>>(H, W2, dinv, Tf, N);
    agg_f16_kernel<true><<<gAgg, 256, 0, stream>>>(Tf, ptr, csr, dinv, b2, H, N);
    // layer 3
    gemm_kernel<64, false><<<gG64, 256, 0, stream>>>(H, W3, dinv, T3, N);
    agg_f32_64_kernel<<<gAgg, 256, 0, stream>>>(T3, ptr, csr, dinv, b3, out, N);
}

// Round 7
// 660.547 us; speedup vs baseline: 1.4561x; 1.2925x over previous
//
#include <hip/hip_runtime.h>
#include <hip/hip_bf16.h>
#include <hip/hip_fp16.h>

// GCN3: 3-layer GCN on MI355X (f32 inputs, fp16 internal message matrix).
// out[i] = dinv[i]*(sum_e ew*Ts[row_e] + Ts[i]) + b, Ts[r] = dinv[r]*(h@W)[r]
// CSC is canonicalized (per-node bitonic segment sort) so every call is
// bit-deterministic; dinv comes from a fixed shuffle-tree over sorted lanes.

#define K_DIM 128

using h2 = __attribute__((ext_vector_type(2))) _Float16;
using h4 = __attribute__((ext_vector_type(4))) _Float16;
using h8 = __attribute__((ext_vector_type(8))) _Float16;

// ---------------- zero counts ----------------
__global__ void zero_kernel(int* __restrict__ cnt, int n) {
    int i = blockIdx.x * blockDim.x + threadIdx.x;
    if (i < n) cnt[i] = 0;
}

// ---------------- histogram: cnt[col]++ (single atomic per edge) ----------------
__global__ void hist_kernel(const int* __restrict__ col, int* __restrict__ cnt, int e) {
    int i = blockIdx.x * blockDim.x + threadIdx.x;
    if (i < e) atomicAdd(&cnt[col[i]], 1);
}

// ---------------- scan part A: per-block exclusive scan + block sums ----------------
__global__ __launch_bounds__(1024) void scanA_kernel(const int* __restrict__ cnt,
                                                     int* __restrict__ excl,   // -> ptr
                                                     int* __restrict__ bsum, int n) {
    __shared__ int wsum[16];
    int t = threadIdx.x, lane = t & 63, wid = t >> 6;
    int i = blockIdx.x * 1024 + t;
    int x = (i < n) ? cnt[i] : 0;
    int v = x;
    #pragma unroll
    for (int d = 1; d < 64; d <<= 1) {
        int y = __shfl_up(v, d, 64);
        if (lane >= d) v += y;
    }
    if (lane == 63) wsum[wid] = v;
    __syncthreads();
    if (wid == 0) {
        int s = (lane < 16) ? wsum[lane] : 0;
        #pragma unroll
        for (int d = 1; d < 16; d <<= 1) {
            int y = __shfl_up(s, d, 64);
            if (lane >= d) s += y;
        }
        if (lane < 16) wsum[lane] = s;
    }
    __syncthreads();
    int woff = (wid > 0) ? wsum[wid - 1] : 0;
    int incl = v + woff;
    if (i < n) excl[i] = incl - x;
    if (t == 1023) bsum[blockIdx.x] = incl;  // block total
}

// ---------------- scan part B: add block offsets; write ptr and fill ptr ----------------
__global__ __launch_bounds__(1024) void scanB_kernel(int* __restrict__ ptr,
                                                     int* __restrict__ fillp,
                                                     const int* __restrict__ bsum,
                                                     int n, int etot) {
    __shared__ int wred[16];
    __shared__ int off_s;
    int t = threadIdx.x, lane = t & 63, wid = t >> 6;
    int p = (t < blockIdx.x) ? bsum[t] : 0;   // blockIdx.x <= 97 < 1024
    #pragma unroll
    for (int d = 32; d; d >>= 1) p += __shfl_down(p, d, 64);
    if (lane == 0) wred[wid] = p;
    __syncthreads();
    if (t == 0) {
        int o = 0;
        #pragma unroll
        for (int j = 0; j < 16; ++j) o += wred[j];
        off_s = o;
    }
    __syncthreads();
    int off = off_s;
    int i = blockIdx.x * 1024 + t;
    if (i < n) {
        int val = ptr[i] + off;
        ptr[i] = val;
        fillp[i] = val;
    }
    if (blockIdx.x == 0 && t == 0) ptr[n] = etot;
}

// ---------------- scatter edges into CSC slots (packed 8B write) ----------------
__global__ void fill_kernel(const int* __restrict__ row, const int* __restrict__ col,
                            const float* __restrict__ ew, int* __restrict__ fillp,
                            int2* __restrict__ csr, int e) {
    int i = blockIdx.x * blockDim.x + threadIdx.x;
    if (i < e) {
        int c = col[i];
        int p = atomicAdd(&fillp[c], 1);
        csr[p] = make_int2(row[i], __float_as_int(ew[i]));
    }
}

// ---------------- canonicalize + dinv: one wave per node, bitonic in-register sort ----
// Sorts each CSC segment by (row, ew_bits) with a 64-wide shfl_xor bitonic network,
// then computes dinv = rsqrt(1 + sum ew) via a fixed shuffle tree (deterministic).
__global__ __launch_bounds__(256) void sortdeg_kernel(int2* __restrict__ csr,
                                                      const int* __restrict__ ptr,
                                                      float* __restrict__ dinv, int n) {
    int node = blockIdx.x * 4 + (threadIdx.x >> 6);
    int lane = threadIdx.x & 63;
    if (node >= n) return;
    int s = ptr[node], e = ptr[node + 1];
    int len = e - s;
    if (len <= 64) {
        int mx = 0x7FFFFFFF;
        unsigned my = 0xFFFFFFFFu;   // sentinel = +inf key
        if (lane < len) {
            int2 v = csr[s + lane];
            mx = v.x; my = (unsigned)v.y;
        }
        #pragma unroll
        for (int k = 2; k <= 64; k <<= 1) {
            #pragma unroll
            for (int j = k >> 1; j > 0; j >>= 1) {
                int ox = __shfl_xor(mx, j, 64);
                unsigned oy = (unsigned)__shfl_xor((int)my, j, 64);
                bool up = ((lane & k) == 0);
                bool lower = ((lane & j) == 0);
                bool keep_min = (up == lower);
                bool me_gt  = (mx > ox) || (mx == ox && my > oy);
                bool oth_gt = (ox > mx) || (ox == mx && oy > my);
                bool take = keep_min ? me_gt : oth_gt;
                if (take) { mx = ox; my = oy; }
            }
        }
        if (lane < len) csr[s + lane] = make_int2(mx, (int)my);
        float w = (lane < len) ? __uint_as_float(my) : 0.f;
        #pragma unroll
        for (int d = 32; d; d >>= 1) w += __shfl_xor(w, d, 64);
        if (lane == 0) dinv[node] = rsqrtf(1.0f + w);
    } else {
        // ultra-rare fallback: serial insertion sort + sequential degree by lane 0
        if (lane == 0) {
            for (int k = s + 1; k < e; ++k) {
                int2 key = csr[k];
                int j = k - 1;
                while (j >= s) {
                    int2 cj = csr[j];
                    bool gt = (cj.x > key.x) ||
                              (cj.x == key.x && (unsigned)cj.y > (unsigned)key.y);
                    if (!gt) break;
                    csr[j + 1] = cj;
                    --j;
                }
                csr[j + 1] = key;
            }
            float sum = 1.0f;
            for (int k = s; k < e; ++k) sum += __int_as_float(csr[k].y);
            dinv[node] = rsqrtf(sum);
        }
    }
}

// ---------------- GEMM: Ts[r, col0:col0+64] = dinv[r] * (A[r,:] @ W[:, col0:col0+64]) ----------------
template <int DOUT, bool FP16OUT>
__global__ __launch_bounds__(256, 2) void gemm_kernel(const float* __restrict__ A,
                                                      const float* __restrict__ W,
                                                      const float* __restrict__ dinv,
                                                      void* __restrict__ Tout, int nrows) {
    constexpr int K = K_DIM;
    constexpr int BM = 64, BN = 64, TM = 4, TN = 4;
    __shared__ float Ws[K][BN];       // 32 KB
    __shared__ float Xs[K][BM + 8];   // 36 KB, transposed X tile, padded
    int t = threadIdx.x;
    int col0 = blockIdx.y * BN;

    // stage W columns [col0, col0+BN)
    const float4* W4 = (const float4*)W;
    for (int i = t; i < K * BN / 4; i += 256) {
        int k = i >> 4;    // BN/4 = 16 float4 per k-row
        int c4 = i & 15;
        float4 v = W4[k * (DOUT / 4) + (col0 >> 2) + c4];
        Ws[k][c4 * 4 + 0] = v.x; Ws[k][c4 * 4 + 1] = v.y;
        Ws[k][c4 * 4 + 2] = v.z; Ws[k][c4 * 4 + 3] = v.w;
    }
    // stage X tile transposed
    int row0 = blockIdx.x * BM;
    for (int i = t; i < BM * K / 4; i += 256) {
        int r = i >> 5;    // K/4 = 32 float4 per row
        int c4 = i & 31;
        float4 v = make_float4(0.f, 0.f, 0.f, 0.f);
        int gr = row0 + r;
        if (gr < nrows) v = ((const float4*)(A + (size_t)gr * K))[c4];
        Xs[c4 * 4 + 0][r] = v.x; Xs[c4 * 4 + 1][r] = v.y;
        Xs[c4 * 4 + 2][r] = v.z; Xs[c4 * 4 + 3][r] = v.w;
    }
    __syncthreads();

    int tx = t & 15;   // -> cols col0 + tx*4
    int ty = t >> 4;   // -> rows row0 + ty*4
    float acc[TM][TN] = {};
    #pragma unroll 8
    for (int k = 0; k < K; ++k) {
        float4 av = *(const float4*)&Xs[k][ty * 4];   // broadcast, conflict-free
        float4 bv = *(const float4*)&Ws[k][tx * 4];   // 2-way (free)
        float a[4] = {av.x, av.y, av.z, av.w};
        float b[4] = {bv.x, bv.y, bv.z, bv.w};
        #pragma unroll
        for (int m = 0; m < TM; ++m)
            #pragma unroll
            for (int n = 0; n < TN; ++n) acc[m][n] += a[m] * b[n];
    }

    #pragma unroll
    for (int m = 0; m < TM; ++m) {
        int gr = row0 + ty * TM + m;
        if (gr >= nrows) continue;
        float di = dinv[gr];
        if constexpr (FP16OUT) {
            h4 hv;
            #pragma unroll
            for (int n = 0; n < TN; ++n) hv[n] = (_Float16)(acc[m][n] * di);
            *(h4*)((_Float16*)Tout + (size_t)gr * DOUT + col0 + tx * TN) = hv;
        } else {
            float4 v;
            v.x = acc[m][0] * di; v.y = acc[m][1] * di;
            v.z = acc[m][2] * di; v.w = acc[m][3] * di;
            *(float4*)((float*)Tout + (size_t)gr * DOUT + col0 + tx * TN) = v;
        }
    }
}

// ---------------- aggregation, D=128 fp16 T: 16 lanes/node, h8 loads, 4 nodes/wave ----
template <bool RELU>
__global__ __launch_bounds__(256) void agg_f16_kernel(const _Float16* __restrict__ T,
                                                      const int* __restrict__ ptr,
                                                      const int2* __restrict__ csr,
                                                      const float* __restrict__ dinv,
                                                      const float* __restrict__ bias,
                                                      float* __restrict__ out, int n) {
    int node = blockIdx.x * 16 + (threadIdx.x >> 4);
    int g = threadIdx.x & 15;           // lane within 16-lane group; dims g*8..g*8+7
    if (node >= n) return;
    int s = ptr[node], e = ptr[node + 1];
    float di = dinv[node];
    const h8* Tv = (const h8*)T;        // 16 h8 per row
    float acc[8] = {};
    int k = s;
    for (; k + 1 < e; k += 2) {
        int2 e0 = csr[k], e1 = csr[k + 1];
        h8 v0 = Tv[(size_t)e0.x * 16 + g];
        h8 v1 = Tv[(size_t)e1.x * 16 + g];
        float w0 = __int_as_float(e0.y), w1 = __int_as_float(e1.y);
        #pragma unroll
        for (int j = 0; j < 8; ++j) acc[j] += w0 * (float)v0[j];
        #pragma unroll
        for (int j = 0; j < 8; ++j) acc[j] += w1 * (float)v1[j];
    }
    if (k < e) {
        int2 e0 = csr[k];
        h8 v0 = Tv[(size_t)e0.x * 16 + g];
        float w0 = __int_as_float(e0.y);
        #pragma unroll
        for (int j = 0; j < 8; ++j) acc[j] += w0 * (float)v0[j];
    }
    h8 hs = Tv[(size_t)node * 16 + g];  // self term: + Ts[i]
    #pragma unroll
    for (int j = 0; j < 8; ++j) acc[j] += (float)hs[j];
    float4 b0 = ((const float4*)bias)[g * 2];
    float4 b1 = ((const float4*)bias)[g * 2 + 1];
    float4 o0, o1;
    o0.x = di * acc[0] + b0.x; o0.y = di * acc[1] + b0.y;
    o0.z = di * acc[2] + b0.z; o0.w = di * acc[3] + b0.w;
    o1.x = di * acc[4] + b1.x; o1.y = di * acc[5] + b1.y;
    o1.z = di * acc[6] + b1.z; o1.w = di * acc[7] + b1.w;
    if (RELU) {
        o0.x = fmaxf(o0.x, 0.f); o0.y = fmaxf(o0.y, 0.f);
        o0.z = fmaxf(o0.z, 0.f); o0.w = fmaxf(o0.w, 0.f);
        o1.x = fmaxf(o1.x, 0.f); o1.y = fmaxf(o1.y, 0.f);
        o1.z = fmaxf(o1.z, 0.f); o1.w = fmaxf(o1.w, 0.f);
    }
    ((float4*)out)[(size_t)node * 32 + g * 2] = o0;
    ((float4*)out)[(size_t)node * 32 + g * 2 + 1] = o1;
}

// ---------------- aggregation, D=64 f32 T (layer 3): 16 lanes/node, float4 loads ----
__global__ __launch_bounds__(256) void agg_f32_64_kernel(const float* __restrict__ T,
                                                         const int* __restrict__ ptr,
                                                         const int2* __restrict__ csr,
                                                         const float* __restrict__ dinv,
                                                         const float* __restrict__ bias,
                                                         float* __restrict__ out, int n) {
    int node = blockIdx.x * 16 + (threadIdx.x >> 4);
    int g = threadIdx.x & 15;           // dims g*4..g*4+3
    if (node >= n) return;
    int s = ptr[node], e = ptr[node + 1];
    float di = dinv[node];
    const float4* Tv = (const float4*)T;  // 16 float4 per row
    float ax = 0.f, ay = 0.f, az = 0.f, aw = 0.f;
    int k = s;
    for (; k + 1 < e; k += 2) {
        int2 e0 = csr[k], e1 = csr[k + 1];
        float4 v0 = Tv[(size_t)e0.x * 16 + g];
        float4 v1 = Tv[(size_t)e1.x * 16 + g];
        float w0 = __int_as_float(e0.y), w1 = __int_as_float(e1.y);
        ax += w0 * v0.x; ay += w0 * v0.y; az += w0 * v0.z; aw += w0 * v0.w;
        ax += w1 * v1.x; ay += w1 * v1.y; az += w1 * v1.z; aw += w1 * v1.w;
    }
    if (k < e) {
        int2 e0 = csr[k];
        float4 v0 = Tv[(size_t)e0.x * 16 + g];
        float w0 = __int_as_float(e0.y);
        ax += w0 * v0.x; ay += w0 * v0.y; az += w0 * v0.z; aw += w0 * v0.w;
    }
    float4 hs = Tv[(size_t)node * 16 + g];  // self term
    ax += hs.x; ay += hs.y; az += hs.z; aw += hs.w;
    float4 bv = ((const float4*)bias)[g];
    float4 o;
    o.x = di * ax + bv.x; o.y = di * ay + bv.y;
    o.z = di * az + bv.z; o.w = di * aw + bv.w;
    ((float4*)out)[(size_t)node * 16 + g] = o;
}

extern "C" void kernel_launch(void* const* d_in, const int* in_sizes, int n_in,
                              void* d_out, int out_size, void* d_ws, size_t ws_size,
                              hipStream_t stream) {
    const float* x   = (const float*)d_in[0];
    const int* eidx  = (const int*)d_in[1];
    const float* ew  = (const float*)d_in[2];
    const float* W1  = (const float*)d_in[3];
    const float* b1  = (const float*)d_in[4];
    const float* W2  = (const float*)d_in[5];
    const float* b2  = (const float*)d_in[6];
    const float* W3  = (const float*)d_in[7];
    const float* b3  = (const float*)d_in[8];

    const int N = in_sizes[0] / K_DIM;
    const int E = in_sizes[2];
    const int* erow = eidx;
    const int* ecol = eidx + E;

    size_t off = 0;
    auto carve = [&](size_t bytes) {
        char* p = (char*)d_ws + off;
        off += (bytes + 255) & ~(size_t)255;
        return (void*)p;
    };
    int*   cnt  = (int*)carve((size_t)N * 4);          // counts, then fill pointers
    int*   ptr  = (int*)carve((size_t)(N + 1) * 4);    // CSC offsets
    int*   bsum = (int*)carve(128 * 4);                // block sums for scan
    float* dinv = (float*)carve((size_t)N * 4);
    int2*  csr  = (int2*)carve((size_t)E * 8);         // packed {row, ew_bits}
    _Float16* Tf = (_Float16*)carve((size_t)N * 128 * 2);  // fp16 Ts (layers 1-2)
    float* H    = (float*)carve((size_t)N * 128 * 4);      // f32 activations
    float* T3   = (float*)carve((size_t)N * 64 * 4);       // f32 Ts (layer 3)
    (void)ws_size;

    float* out = (float*)d_out;

    const int BT = 256;
    int gN = (N + BT - 1) / BT;
    int gE = (E + BT - 1) / BT;
    int nScan = (N + 1023) / 1024;

    // ---- CSC build + canonicalize + norm ----
    zero_kernel<<<gN, BT, 0, stream>>>(cnt, N);
    hist_kernel<<<gE, BT, 0, stream>>>(ecol, cnt, E);
    scanA_kernel<<<nScan, 1024, 0, stream>>>(cnt, ptr, bsum, N);
    scanB_kernel<<<nScan, 1024, 0, stream>>>(ptr, cnt, bsum, N, E);
    fill_kernel<<<gE, BT, 0, stream>>>(erow, ecol, ew, cnt, csr, E);
    sortdeg_kernel<<<(N + 3) / 4, 256, 0, stream>>>(csr, ptr, dinv, N);

    dim3 gG128((N + 63) / 64, 2);
    dim3 gG64((N + 63) / 64, 1);
    int gAgg16 = (N + 15) / 16;

    // layer 1
    gemm_kernel<128, true><<<gG128, 256, 0, stream>>>(x, W1, dinv, Tf, N);
    agg_f16_kernel<true><<<gAgg16, 256, 0, stream>>>(Tf, ptr, csr, dinv, b1, H, N);
    // layer 2
    gemm_kernel<128, true><<<gG128, 256, 0, stream>>>(H, W2, dinv, Tf, N);
    agg_f16_kernel<true><<<gAgg16, 256, 0, stream>>>(Tf, ptr, csr, dinv, b2, H, N);
    // layer 3
    gemm_kernel<64, false><<<gG64, 256, 0, stream>>>(H, W3, dinv, T3, N);
    agg_f32_64_kernel<<<gAgg16, 256, 0, stream>>>(T3, ptr, csr, dinv, b3, out, N);
}